// Round 5
// baseline (277.789 us; speedup 1.0000x reference)
//
#include <hip/hip_runtime.h>
#include <hip/hip_fp16.h>
#include <math.h>

#define KSIZE 31
#define HRAD 15
#define TR 8   // output rows per blur_v4 block

union H4U { float2 f2; __half h[4]; };
union H8U { float4 f4; __half h[8]; };

// ---------------------------------------------------------------------------
// Cube-map coordinate math (mirrors reference cube_sample exactly, f32)
// ---------------------------------------------------------------------------
__device__ inline void cube_coords(float x, float y, float z,
                                   int& face, float& u, float& v) {
    float ax = fabsf(x), ay = fabsf(y), az = fabsf(z);
    bool is_x = (ax >= ay) && (ax >= az);
    bool is_y = (!is_x) && (ay >= az);
    float ma, sc, tc;
    if (is_x) {
        if (x >= 0.0f) { face = 0; sc = -z; } else { face = 1; sc = z; }
        ma = ax; tc = -y;
    } else if (is_y) {
        if (y >= 0.0f) { face = 2; tc = z; } else { face = 3; tc = -z; }
        ma = ay; sc = x;
    } else {
        if (z >= 0.0f) { face = 4; sc = x; } else { face = 5; sc = -x; }
        ma = az; tc = -y;
    }
    float inv = 1.0f / fmaxf(ma, 1e-12f);
    u = 0.5f * (sc * inv + 1.0f);
    v = 0.5f * (tc * inv + 1.0f);
}

// ---------------------------------------------------------------------------
// Neighborhood records: per texel (x,y), 32B = 4 half4 corners
//   [t(x,y), t(x1,y)] [t(x,y1), t(x1,y1)], x1/y1 clamped at build time.
// Left/top edge (floor < 0) handled by forcing wx/wy = 0 (exact: ref blends
// two identical corner texels there).
// ---------------------------------------------------------------------------
__device__ inline void nb_setup(float u, float v, int HW, int face,
                                int& rec, float& wx, float& wy) {
    float fx = u * (float)HW - 0.5f;
    float fy = v * (float)HW - 0.5f;
    float x0 = floorf(fx), y0 = floorf(fy);
    wx = fx - x0;
    wy = fy - y0;
    int xi = (int)x0, yi = (int)y0;
    if (xi < 0) { xi = 0; wx = 0.0f; }
    if (yi < 0) { yi = 0; wy = 0.0f; }
    rec = (face * HW + yi) * HW + xi;
}

__device__ inline void nb_fetch(const float4* __restrict__ nb, int rec,
                                float wx, float wy, float c[3]) {
    H8U qa, qb;
    qa.f4 = nb[(size_t)rec * 2 + 0];
    qb.f4 = nb[(size_t)rec * 2 + 1];
#pragma unroll
    for (int k = 0; k < 3; ++k) {
        float top = __half2float(qa.h[k]) * (1.0f - wx) + __half2float(qa.h[4 + k]) * wx;
        float bot = __half2float(qb.h[k]) * (1.0f - wx) + __half2float(qb.h[4 + k]) * wx;
        c[k] = top * (1.0f - wy) + bot * wy;
    }
}

// ---------------------------------------------------------------------------
// Legacy 8B-texel 2-row-paired tiled layout (fallback for bg1 if ws small)
// ---------------------------------------------------------------------------
struct BLT {
    int i00, i10, i01, i11;
    float wx, wy;
};

__device__ inline BLT bl_tiled(float u, float v, int H, int W, int face) {
    float fx = u * (float)W - 0.5f;
    float fy = v * (float)H - 0.5f;
    float x0 = floorf(fx), y0 = floorf(fy);
    BLT b;
    b.wx = fx - x0;
    b.wy = fy - y0;
    int x0i = min(max((int)x0, 0), W - 1);
    int x1i = min(max((int)x0 + 1, 0), W - 1);
    int y0i = min(max((int)y0, 0), H - 1);
    int y1i = min(max((int)y0 + 1, 0), H - 1);
    int fb = face * (H >> 1);
    int r0 = (fb + (y0i >> 1)) * W;
    int r1 = (fb + (y1i >> 1)) * W;
    b.i00 = (r0 + x0i) * 2 + (y0i & 1);
    b.i10 = (r0 + x1i) * 2 + (y0i & 1);
    b.i01 = (r1 + x0i) * 2 + (y1i & 1);
    b.i11 = (r1 + x1i) * 2 + (y1i & 1);
    return b;
}

__device__ inline void fetch_bl(const float2* __restrict__ tex,
                                const BLT& b, float c[3]) {
    H4U t00, t10, t01, t11;
    t00.f2 = tex[b.i00];
    t10.f2 = tex[b.i10];
    t01.f2 = tex[b.i01];
    t11.f2 = tex[b.i11];
    float wx = b.wx, wy = b.wy;
#pragma unroll
    for (int k = 0; k < 3; ++k) {
        float top = __half2float(t00.h[k]) * (1.0f - wx) + __half2float(t10.h[k]) * wx;
        float bot = __half2float(t01.h[k]) * (1.0f - wx) + __half2float(t11.h[k]) * wx;
        c[k] = top * (1.0f - wy) + bot * wy;
    }
}

// ---------------------------------------------------------------------------
// Interleaved blur records: per 128-map texel, 4 levels x half4 = 32B.
// record index rec = ((face*64 + y/2)*128 + x)*2 + (y&1)
// ---------------------------------------------------------------------------
struct BLR {
    int r00, r10, r01, r11;
    float wx, wy;
};

__device__ inline BLR bl_rec(float u, float v, int face) {
    float fx = u * 128.0f - 0.5f;
    float fy = v * 128.0f - 0.5f;
    float x0 = floorf(fx), y0 = floorf(fy);
    BLR b;
    b.wx = fx - x0;
    b.wy = fy - y0;
    int x0i = min(max((int)x0, 0), 127);
    int x1i = min(max((int)x0 + 1, 0), 127);
    int y0i = min(max((int)y0, 0), 127);
    int y1i = min(max((int)y0 + 1, 0), 127);
    int fb = face * 64;
    int r0 = (fb + (y0i >> 1)) * 128;
    int r1 = (fb + (y1i >> 1)) * 128;
    b.r00 = (r0 + x0i) * 2 + (y0i & 1);
    b.r10 = (r0 + x1i) * 2 + (y0i & 1);
    b.r01 = (r1 + x0i) * 2 + (y1i & 1);
    b.r11 = (r1 + x1i) * 2 + (y1i & 1);
    return b;
}

__device__ inline void accum_level(const H8U& q00, const H8U& q10,
                                   const H8U& q01, const H8U& q11,
                                   int off, float w, float wx, float wy,
                                   float& b0, float& b1, float& b2) {
    float c[3];
#pragma unroll
    for (int k = 0; k < 3; ++k) {
        float top = __half2float(q00.h[off + k]) * (1.0f - wx) + __half2float(q10.h[off + k]) * wx;
        float bot = __half2float(q01.h[off + k]) * (1.0f - wx) + __half2float(q11.h[off + k]) * wx;
        c[k] = top * (1.0f - wy) + bot * wy;
    }
    b0 += w * c[0];
    b1 += w * c[1];
    b2 += w * c[2];
}

// ---------------------------------------------------------------------------
// Inline f32 Gaussian weights: tid 0..127 -> (lvl = tid/32, tap = tid%32).
// Normalization within each 32-lane group via shfl_xor.
// ---------------------------------------------------------------------------
__device__ inline void weights_inline(int tid, float wS[4][32]) {
    const float ss[4] = {8.f, 4.f, 2.f, 1.f};
    int lvl = tid >> 5;
    int tap = tid & 31;
    float d = (float)tap - 15.0f;
    float q = d / ss[lvl];
    float g = (tap < KSIZE) ? expf(-0.5f * q * q) : 0.0f;
    float s = g;
#pragma unroll
    for (int k = 16; k; k >>= 1) s += __shfl_xor(s, k, 32);
    wS[lvl][tap] = g / s;
}

// ---------------------------------------------------------------------------
// Horizontal blur, 4 levels per block. blockIdx = face*128 + yrow.
// ---------------------------------------------------------------------------
__global__ __launch_bounds__(128)
void blur_h4(const float* __restrict__ bg0, float* __restrict__ tmp) {
    __shared__ float wS[4][32];
    __shared__ float row[128 * 3];
    int bid  = blockIdx.x;
    int yrow = bid & 127;
    int face = bid >> 7;
    int tid  = threadIdx.x;

    weights_inline(tid, wS);
    const float* src = bg0 + (size_t)(face * 128 + yrow) * 384;
    for (int k = tid; k < 384; k += 128) row[k] = src[k];
    __syncthreads();

    int x = tid;
    float a[4][3] = {};
    for (int t = 0; t < KSIZE; ++t) {
        int xx = x + t - HRAD;
        if (xx >= 0 && xx < 128) {
            float r0 = row[xx * 3 + 0];
            float r1 = row[xx * 3 + 1];
            float r2 = row[xx * 3 + 2];
#pragma unroll
            for (int l = 0; l < 4; ++l) {
                float w = wS[l][t];
                a[l][0] += w * r0; a[l][1] += w * r1; a[l][2] += w * r2;
            }
        }
    }
#pragma unroll
    for (int l = 0; l < 4; ++l) {
        float* dst = tmp + ((size_t)((l * 6 + face) * 128 + yrow) * 128 + x) * 3;
        dst[0] = a[l][0]; dst[1] = a[l][1]; dst[2] = a[l][2];
    }
}

// ---------------------------------------------------------------------------
// Vertical blur: TR output rows per block, LDS row staging, sliding
// accumulators.  blockIdx = face*16 + rowtile.  128 threads = one per x.
// ---------------------------------------------------------------------------
__global__ __launch_bounds__(128)
void blur_v4(const float* __restrict__ tmp, float4* __restrict__ blurp) {
    __shared__ float wS[4][32];
    __shared__ float rows[TR + 30][384];
    int bid   = blockIdx.x;
    int face  = bid >> 4;
    int ytile = (bid & 15) * TR;
    int tid   = threadIdx.x;

    weights_inline(tid, wS);

    H8U recA[TR], recB[TR];
#pragma unroll
    for (int lvl = 0; lvl < 4; ++lvl) {
        __syncthreads();   // weights visible (lvl 0); prior level reads done
        const float* base = tmp + (size_t)(lvl * 6 + face) * 128 * 384;
        for (int i = tid; i < (TR + 30) * 384; i += 128) {
            int ly = i / 384, off = i - ly * 384;
            int gy = ytile - 15 + ly;
            rows[ly][off] = (gy >= 0 && gy < 128) ? base[(size_t)gy * 384 + off] : 0.0f;
        }
        __syncthreads();

        float acc[TR][3] = {};
        for (int ly = 0; ly < TR + 30; ++ly) {
            float r0 = rows[ly][tid * 3 + 0];
            float r1 = rows[ly][tid * 3 + 1];
            float r2 = rows[ly][tid * 3 + 2];
#pragma unroll
            for (int oy = 0; oy < TR; ++oy) {
                int t = ly - oy;
                if (t >= 0 && t < KSIZE) {
                    float w = wS[lvl][t];
                    acc[oy][0] += w * r0; acc[oy][1] += w * r1; acc[oy][2] += w * r2;
                }
            }
        }
#pragma unroll
        for (int oy = 0; oy < TR; ++oy) {
            H8U& r = (lvl < 2) ? recA[oy] : recB[oy];
            int off = (lvl & 1) * 4;
            r.h[off + 0] = __float2half(acc[oy][0]);
            r.h[off + 1] = __float2half(acc[oy][1]);
            r.h[off + 2] = __float2half(acc[oy][2]);
            r.h[off + 3] = __float2half(0.0f);
        }
    }
#pragma unroll
    for (int oy = 0; oy < TR; ++oy) {
        int y = ytile + oy;
        int rec = ((face * 64 + (y >> 1)) * 128 + tid) * 2 + (y & 1);
        blurp[(size_t)rec * 2 + 0] = recA[oy].f4;
        blurp[(size_t)rec * 2 + 1] = recB[oy].f4;
    }
}

// ---------------------------------------------------------------------------
// Build neighborhood records from f32 RGB cube map (LDS-tiled, 16x16 recs).
// ---------------------------------------------------------------------------
template <int W>
__global__ __launch_bounds__(256)
void pack_nbhd(const float* __restrict__ src, float4* __restrict__ dst) {
    __shared__ float t[17][17 * 3];
    const int TB = W / 16;
    int bx = blockIdx.x % TB;
    int by = (blockIdx.x / TB) % TB;
    int f  = blockIdx.x / (TB * TB);

    for (int i = threadIdx.x; i < 17 * 17; i += 256) {
        int lx = i % 17, ly = i / 17;
        int gx = min(bx * 16 + lx, W - 1);
        int gy = min(by * 16 + ly, W - 1);
        const float* p = src + ((size_t)(f * W + gy) * W + gx) * 3;
        t[ly][lx * 3 + 0] = p[0];
        t[ly][lx * 3 + 1] = p[1];
        t[ly][lx * 3 + 2] = p[2];
    }
    __syncthreads();

    int tx = threadIdx.x & 15, ty = threadIdx.x >> 4;
    H8U qa, qb;
#pragma unroll
    for (int k = 0; k < 3; ++k) {
        qa.h[k]     = __float2half(t[ty][tx * 3 + k]);
        qa.h[4 + k] = __float2half(t[ty][(tx + 1) * 3 + k]);
        qb.h[k]     = __float2half(t[ty + 1][tx * 3 + k]);
        qb.h[4 + k] = __float2half(t[ty + 1][(tx + 1) * 3 + k]);
    }
    qa.h[3] = __float2half(0.0f); qa.h[7] = __float2half(0.0f);
    qb.h[3] = __float2half(0.0f); qb.h[7] = __float2half(0.0f);

    size_t rec = (size_t)(f * W + by * 16 + ty) * W + bx * 16 + tx;
    dst[rec * 2 + 0] = qa.f4;
    dst[rec * 2 + 1] = qb.f4;
}

// ---------------------------------------------------------------------------
// Fallback pack: f32 RGB -> 8B half4 tiled (bg1 only, if ws too small)
// ---------------------------------------------------------------------------
__global__ __launch_bounds__(256)
void pack_tiled(const float* __restrict__ src, float2* __restrict__ dst,
                int H, int W, int total) {
    int i = blockIdx.x * blockDim.x + threadIdx.x;
    if (i >= total) return;
    int x = i % W;
    int y = (i / W) % H;
    int f = i / (W * H);
    H4U u;
    u.h[0] = __float2half(src[(size_t)i * 3 + 0]);
    u.h[1] = __float2half(src[(size_t)i * 3 + 1]);
    u.h[2] = __float2half(src[(size_t)i * 3 + 2]);
    u.h[3] = __float2half(0.0f);
    int idx = ((f * (H >> 1) + (y >> 1)) * W + x) * 2 + (y & 1);
    dst[idx] = u.f2;
}

// ---------------------------------------------------------------------------
// Per-ray shading body
// ---------------------------------------------------------------------------
template <bool NB1>
__device__ inline void shade_one(float x, float y, float z, float sa,
                                 const float4* __restrict__ bg0n,
                                 const float4* __restrict__ bg1n,
                                 const float2* __restrict__ bg1p,
                                 const float4* __restrict__ blurp,
                                 float* __restrict__ R) {
    int face; float u, v;
    cube_coords(x, y, z, face, u, v);

    const float saTexel = (float)(4.0 * M_PI / (6.0 * 512.0 * 512.0));
    float m = logf(sa / saTexel);
    m = m / 1.3862943611198906f;   // f32(log(4))
    m = m * 0.5f;
    m = fminf(fmaxf(m, 0.0f), 3.0f);

    if (m >= 2.0f) {
        BLR b = bl_rec(u, v, face);
        H8U q00a, q00b, q10a, q10b, q01a, q01b, q11a, q11b;
        q00a.f4 = blurp[b.r00 * 2 + 0]; q00b.f4 = blurp[b.r00 * 2 + 1];
        q10a.f4 = blurp[b.r10 * 2 + 0]; q10b.f4 = blurp[b.r10 * 2 + 1];
        q01a.f4 = blurp[b.r01 * 2 + 0]; q01b.f4 = blurp[b.r01 * 2 + 1];
        q11a.f4 = blurp[b.r11 * 2 + 0]; q11b.f4 = blurp[b.r11 * 2 + 1];

        float w0 = 1.0f - fminf(fabsf(3.0f - m), 1.0f);
        float w1 = 1.0f - fminf(fabsf(2.5f - m), 1.0f);
        float w2 = 1.0f - fminf(fabsf(2.0f - m), 1.0f);
        float w3 = 1.0f - fminf(fabsf(1.5f - m), 1.0f);

        float b0 = 0.f, b1 = 0.f, b2 = 0.f;
        accum_level(q00a, q10a, q01a, q11a, 0, w0, b.wx, b.wy, b0, b1, b2);
        accum_level(q00a, q10a, q01a, q11a, 4, w1, b.wx, b.wy, b0, b1, b2);
        accum_level(q00b, q10b, q01b, q11b, 0, w2, b.wx, b.wy, b0, b1, b2);
        accum_level(q00b, q10b, q01b, q11b, 4, w3, b.wx, b.wy, b0, b1, b2);

        float denom = fmaxf(w0 + w1 + w2 + w3, 1e-8f);
        R[0] = b0 / denom; R[1] = b1 / denom; R[2] = b2 / denom;
    } else {
        int r0i; float wx0, wy0;
        nb_setup(u, v, 128, face, r0i, wx0, wy0);
        float c0[3], c1[3];
        nb_fetch(bg0n, r0i, wx0, wy0, c0);
        if (NB1) {
            int r1i; float wx1, wy1;
            nb_setup(u, v, 512, face, r1i, wx1, wy1);
            nb_fetch(bg1n, r1i, wx1, wy1, c1);
        } else {
            BLT b512 = bl_tiled(u, v, 512, 512, face);
            fetch_bl(bg1p, b512, c1);
        }
        R[0] = c0[0] + 0.5f * c1[0];
        R[1] = c0[1] + 0.5f * c1[1];
        R[2] = c0[2] + 0.5f * c1[2];
    }
}

// ---------------------------------------------------------------------------
// Shade: 4 rays per thread, vectorized stream I/O.
// ---------------------------------------------------------------------------
template <bool NB1>
__global__ __launch_bounds__(256)
void shade4(const float4* __restrict__ vd4, const float4* __restrict__ sa4,
            const float4* __restrict__ bg0n, const float4* __restrict__ bg1n,
            const float2* __restrict__ bg1p, const float4* __restrict__ blurp,
            float4* __restrict__ out4, int nquads) {
    int q = blockIdx.x * blockDim.x + threadIdx.x;
    if (q >= nquads) return;

    float4 a = vd4[3 * q + 0];
    float4 b = vd4[3 * q + 1];
    float4 c = vd4[3 * q + 2];
    float4 s = sa4[q];

    float X[4] = {a.x, a.w, b.z, c.y};
    float Y[4] = {a.y, b.x, b.w, c.z};
    float Z[4] = {a.z, b.y, c.x, c.w};
    float S[4] = {s.x, s.y, s.z, s.w};

    float R[12];
#pragma unroll
    for (int r = 0; r < 4; ++r) {
        shade_one<NB1>(X[r], Y[r], Z[r], S[r], bg0n, bg1n, bg1p, blurp, &R[3 * r]);
    }

    out4[3 * q + 0] = make_float4(R[0], R[1], R[2],  R[3]);
    out4[3 * q + 1] = make_float4(R[4], R[5], R[6],  R[7]);
    out4[3 * q + 2] = make_float4(R[8], R[9], R[10], R[11]);
}

// ---------------------------------------------------------------------------
extern "C" void kernel_launch(void* const* d_in, const int* in_sizes, int n_in,
                              void* d_out, int out_size, void* d_ws, size_t ws_size,
                              hipStream_t stream) {
    const float* viewdirs = (const float*)d_in[0];   // (B,3)
    const float* saSample = (const float*)d_in[1];   // (B,1)
    const float* bg0      = (const float*)d_in[2];   // (6,128,128,3)
    const float* bg1      = (const float*)d_in[3];   // (6,512,512,3)
    float* out = (float*)d_out;

    int B = in_sizes[0] / 3;

    // ws layout (nbhd mode, 56.6 MB):
    //   blurp : 196608 float4 (3.0 MB)
    //   bg0n  : 196608 float4 (3.0 MB)
    //   bg1n  : 3145728 float4 (50.3 MB)  -- tmp (4.7 MB) aliases its head
    // fallback (18.9 MB): bg1p (12.6 MB) instead of bg1n, tmp aliases bg1p.
    float4* blurp = (float4*)d_ws;
    float4* bg0n  = blurp + 196608;
    const size_t NEED_NB = (size_t)(196608 + 196608 + 3145728) * 16;
    bool nb1 = ws_size >= NEED_NB;

    float4* bg1n = bg0n + 196608;
    float2* bg1p = (float2*)(bg0n + 196608);
    float*  tmp  = (float*)(bg0n + 196608);   // alias; dead before bg1 pack

    blur_h4<<<6 * 128, 128, 0, stream>>>(bg0, tmp);
    blur_v4<<<6 * 16, 128, 0, stream>>>(tmp, blurp);

    pack_nbhd<128><<<6 * 8 * 8, 256, 0, stream>>>(bg0, bg0n);
    if (nb1) {
        pack_nbhd<512><<<6 * 32 * 32, 256, 0, stream>>>(bg1, bg1n);
    } else {
        int t1 = 6 * 512 * 512;
        pack_tiled<<<(t1 + 255) / 256, 256, 0, stream>>>(bg1, bg1p, 512, 512, t1);
    }

    int nquads = B / 4;
    int blocks = (nquads + 255) / 256;
    if (nb1) {
        shade4<true><<<blocks, 256, 0, stream>>>((const float4*)viewdirs,
                                                 (const float4*)saSample,
                                                 bg0n, bg1n, bg1p, blurp,
                                                 (float4*)out, nquads);
    } else {
        shade4<false><<<blocks, 256, 0, stream>>>((const float4*)viewdirs,
                                                  (const float4*)saSample,
                                                  bg0n, bg1n, bg1p, blurp,
                                                  (float4*)out, nquads);
    }
}

// Round 6
// 112.568 us; speedup vs baseline: 2.4677x; 2.4677x over previous
//
#include <hip/hip_runtime.h>
#include <hip/hip_fp16.h>
#include <math.h>

#define KSIZE 31
#define HRAD 15

union H4U { float2 f2; __half h[4]; };
union H8U { float4 f4; __half h[8]; };

// ---------------------------------------------------------------------------
// Cube-map coordinate math (mirrors reference cube_sample exactly, f32)
// ---------------------------------------------------------------------------
__device__ inline void cube_coords(float x, float y, float z,
                                   int& face, float& u, float& v) {
    float ax = fabsf(x), ay = fabsf(y), az = fabsf(z);
    bool is_x = (ax >= ay) && (ax >= az);
    bool is_y = (!is_x) && (ay >= az);
    float ma, sc, tc;
    if (is_x) {
        if (x >= 0.0f) { face = 0; sc = -z; } else { face = 1; sc = z; }
        ma = ax; tc = -y;
    } else if (is_y) {
        if (y >= 0.0f) { face = 2; tc = z; } else { face = 3; tc = -z; }
        ma = ay; sc = x;
    } else {
        if (z >= 0.0f) { face = 4; sc = x; } else { face = 5; sc = -x; }
        ma = az; tc = -y;
    }
    float inv = 1.0f / fmaxf(ma, 1e-12f);
    u = 0.5f * (sc * inv + 1.0f);
    v = 0.5f * (tc * inv + 1.0f);
}

// ---------------------------------------------------------------------------
// Neighborhood records: per texel (x,y), 32B = 4 half4 corners
//   [t(x,y), t(x1,y)] [t(x,y1), t(x1,y1)], x1/y1 clamped at build time.
// Left/top edge (floor < 0): force wx/wy = 0 (exact).
// ---------------------------------------------------------------------------
__device__ inline void nb_setup(float u, float v, int HW, int face,
                                int& rec, float& wx, float& wy) {
    float fx = u * (float)HW - 0.5f;
    float fy = v * (float)HW - 0.5f;
    float x0 = floorf(fx), y0 = floorf(fy);
    wx = fx - x0;
    wy = fy - y0;
    int xi = (int)x0, yi = (int)y0;
    if (xi < 0) { xi = 0; wx = 0.0f; }
    if (yi < 0) { yi = 0; wy = 0.0f; }
    rec = (face * HW + yi) * HW + xi;
}

__device__ inline void nb_fetch(const float4* __restrict__ nb, int rec,
                                float wx, float wy, float c[3]) {
    H8U qa, qb;
    qa.f4 = nb[(size_t)rec * 2 + 0];
    qb.f4 = nb[(size_t)rec * 2 + 1];
#pragma unroll
    for (int k = 0; k < 3; ++k) {
        float top = __half2float(qa.h[k]) * (1.0f - wx) + __half2float(qa.h[4 + k]) * wx;
        float bot = __half2float(qb.h[k]) * (1.0f - wx) + __half2float(qb.h[4 + k]) * wx;
        c[k] = top * (1.0f - wy) + bot * wy;
    }
}

// ---------------------------------------------------------------------------
// Legacy 8B-texel 2-row-paired tiled layout (fallback for bg1 if ws small)
// ---------------------------------------------------------------------------
struct BLT {
    int i00, i10, i01, i11;
    float wx, wy;
};

__device__ inline BLT bl_tiled(float u, float v, int H, int W, int face) {
    float fx = u * (float)W - 0.5f;
    float fy = v * (float)H - 0.5f;
    float x0 = floorf(fx), y0 = floorf(fy);
    BLT b;
    b.wx = fx - x0;
    b.wy = fy - y0;
    int x0i = min(max((int)x0, 0), W - 1);
    int x1i = min(max((int)x0 + 1, 0), W - 1);
    int y0i = min(max((int)y0, 0), H - 1);
    int y1i = min(max((int)y0 + 1, 0), H - 1);
    int fb = face * (H >> 1);
    int r0 = (fb + (y0i >> 1)) * W;
    int r1 = (fb + (y1i >> 1)) * W;
    b.i00 = (r0 + x0i) * 2 + (y0i & 1);
    b.i10 = (r0 + x1i) * 2 + (y0i & 1);
    b.i01 = (r1 + x0i) * 2 + (y1i & 1);
    b.i11 = (r1 + x1i) * 2 + (y1i & 1);
    return b;
}

__device__ inline void fetch_bl(const float2* __restrict__ tex,
                                const BLT& b, float c[3]) {
    H4U t00, t10, t01, t11;
    t00.f2 = tex[b.i00];
    t10.f2 = tex[b.i10];
    t01.f2 = tex[b.i01];
    t11.f2 = tex[b.i11];
    float wx = b.wx, wy = b.wy;
#pragma unroll
    for (int k = 0; k < 3; ++k) {
        float top = __half2float(t00.h[k]) * (1.0f - wx) + __half2float(t10.h[k]) * wx;
        float bot = __half2float(t01.h[k]) * (1.0f - wx) + __half2float(t11.h[k]) * wx;
        c[k] = top * (1.0f - wy) + bot * wy;
    }
}

// ---------------------------------------------------------------------------
// Interleaved blur records: per 128-map texel, 4 levels x half4 = 32B.
// record index rec = ((face*64 + y/2)*128 + x)*2 + (y&1)
// ---------------------------------------------------------------------------
struct BLR {
    int r00, r10, r01, r11;
    float wx, wy;
};

__device__ inline BLR bl_rec(float u, float v, int face) {
    float fx = u * 128.0f - 0.5f;
    float fy = v * 128.0f - 0.5f;
    float x0 = floorf(fx), y0 = floorf(fy);
    BLR b;
    b.wx = fx - x0;
    b.wy = fy - y0;
    int x0i = min(max((int)x0, 0), 127);
    int x1i = min(max((int)x0 + 1, 0), 127);
    int y0i = min(max((int)y0, 0), 127);
    int y1i = min(max((int)y0 + 1, 0), 127);
    int fb = face * 64;
    int r0 = (fb + (y0i >> 1)) * 128;
    int r1 = (fb + (y1i >> 1)) * 128;
    b.r00 = (r0 + x0i) * 2 + (y0i & 1);
    b.r10 = (r0 + x1i) * 2 + (y0i & 1);
    b.r01 = (r1 + x0i) * 2 + (y1i & 1);
    b.r11 = (r1 + x1i) * 2 + (y1i & 1);
    return b;
}

__device__ inline void accum_level(const H8U& q00, const H8U& q10,
                                   const H8U& q01, const H8U& q11,
                                   int off, float w, float wx, float wy,
                                   float& b0, float& b1, float& b2) {
    float c[3];
#pragma unroll
    for (int k = 0; k < 3; ++k) {
        float top = __half2float(q00.h[off + k]) * (1.0f - wx) + __half2float(q10.h[off + k]) * wx;
        float bot = __half2float(q01.h[off + k]) * (1.0f - wx) + __half2float(q11.h[off + k]) * wx;
        c[k] = top * (1.0f - wy) + bot * wy;
    }
    b0 += w * c[0];
    b1 += w * c[1];
    b2 += w * c[2];
}

// ---------------------------------------------------------------------------
// Inline f32 Gaussian weights: tid 0..127 -> (lvl = tid/32, tap = tid%32).
// ---------------------------------------------------------------------------
__device__ inline void weights_inline(int tid, float wS[4][32]) {
    const float ss[4] = {8.f, 4.f, 2.f, 1.f};
    int lvl = (tid >> 5) & 3;
    int tap = tid & 31;
    float d = (float)tap - 15.0f;
    float q = d / ss[lvl];
    float g = (tap < KSIZE) ? expf(-0.5f * q * q) : 0.0f;
    float s = g;
#pragma unroll
    for (int k = 16; k; k >>= 1) s += __shfl_xor(s, k, 32);
    if (tid < 128) wS[lvl][tap] = g / s;
}

// ---------------------------------------------------------------------------
// Horizontal blur (4 levels) + bg0 neighborhood-record emit, fused.
// blockIdx = face*128 + yrow.  128 threads = one per x.
// tmp layout: [face][y][x][lvl*3+c]  (12 floats = 3 float4 per texel)
// ---------------------------------------------------------------------------
__global__ __launch_bounds__(128)
void blur_h4(const float* __restrict__ bg0, float4* __restrict__ tmp,
             float4* __restrict__ bg0n) {
    __shared__ float wS[4][32];
    __shared__ float rowA[128 * 3];
    __shared__ float rowB[128 * 3];
    int bid  = blockIdx.x;
    int yrow = bid & 127;
    int face = bid >> 7;
    int tid  = threadIdx.x;

    weights_inline(tid, wS);
    int ynext = min(yrow + 1, 127);
    const float* srcA = bg0 + (size_t)(face * 128 + yrow) * 384;
    const float* srcB = bg0 + (size_t)(face * 128 + ynext) * 384;
    for (int k = tid; k < 384; k += 128) { rowA[k] = srcA[k]; rowB[k] = srcB[k]; }
    __syncthreads();

    int x = tid;
    float a[4][3] = {};
    for (int t = 0; t < KSIZE; ++t) {
        int xx = x + t - HRAD;
        if (xx >= 0 && xx < 128) {
            float r0 = rowA[xx * 3 + 0];
            float r1 = rowA[xx * 3 + 1];
            float r2 = rowA[xx * 3 + 2];
#pragma unroll
            for (int l = 0; l < 4; ++l) {
                float w = wS[l][t];
                a[l][0] += w * r0; a[l][1] += w * r1; a[l][2] += w * r2;
            }
        }
    }
    size_t idx = (size_t)(face * 128 + yrow) * 128 + x;
    tmp[idx * 3 + 0] = make_float4(a[0][0], a[0][1], a[0][2], a[1][0]);
    tmp[idx * 3 + 1] = make_float4(a[1][1], a[1][2], a[2][0], a[2][1]);
    tmp[idx * 3 + 2] = make_float4(a[2][2], a[3][0], a[3][1], a[3][2]);

    // bg0 neighborhood record for (x, yrow)
    int x1 = min(x + 1, 127);
    H8U qa, qb;
#pragma unroll
    for (int k = 0; k < 3; ++k) {
        qa.h[k]     = __float2half(rowA[x * 3 + k]);
        qa.h[4 + k] = __float2half(rowA[x1 * 3 + k]);
        qb.h[k]     = __float2half(rowB[x * 3 + k]);
        qb.h[4 + k] = __float2half(rowB[x1 * 3 + k]);
    }
    qa.h[3] = __float2half(0.0f); qa.h[7] = __float2half(0.0f);
    qb.h[3] = __float2half(0.0f); qb.h[7] = __float2half(0.0f);
    bg0n[idx * 2 + 0] = qa.f4;
    bg0n[idx * 2 + 1] = qb.f4;
}

// ---------------------------------------------------------------------------
// Vertical blur: one output row per block (768 blocks), all 4 levels via
// 3 float4 loads per tap row (tmp is level-interleaved, L2-resident).
// ---------------------------------------------------------------------------
__global__ __launch_bounds__(128)
void blur_v4(const float4* __restrict__ tmp, float4* __restrict__ blurp) {
    __shared__ float wS[4][32];
    int bid  = blockIdx.x;
    int yrow = bid & 127;
    int face = bid >> 7;
    int tid  = threadIdx.x;

    weights_inline(tid, wS);
    __syncthreads();

    int x = tid;
    float acc[12] = {};
    int ylo = max(yrow - HRAD, 0);
    int yhi = min(yrow + HRAD, 127);
    for (int yy = ylo; yy <= yhi; ++yy) {
        int t = yy - yrow + HRAD;
        size_t idx = (size_t)(face * 128 + yy) * 128 + x;
        float4 q0 = tmp[idx * 3 + 0];
        float4 q1 = tmp[idx * 3 + 1];
        float4 q2 = tmp[idx * 3 + 2];
        float w0 = wS[0][t], w1 = wS[1][t], w2 = wS[2][t], w3 = wS[3][t];
        acc[0]  += w0 * q0.x; acc[1]  += w0 * q0.y; acc[2]  += w0 * q0.z;
        acc[3]  += w1 * q0.w; acc[4]  += w1 * q1.x; acc[5]  += w1 * q1.y;
        acc[6]  += w2 * q1.z; acc[7]  += w2 * q1.w; acc[8]  += w2 * q2.x;
        acc[9]  += w3 * q2.y; acc[10] += w3 * q2.z; acc[11] += w3 * q2.w;
    }

    H8U ra, rb;
#pragma unroll
    for (int l = 0; l < 2; ++l) {
        ra.h[l * 4 + 0] = __float2half(acc[l * 3 + 0]);
        ra.h[l * 4 + 1] = __float2half(acc[l * 3 + 1]);
        ra.h[l * 4 + 2] = __float2half(acc[l * 3 + 2]);
        ra.h[l * 4 + 3] = __float2half(0.0f);
        rb.h[l * 4 + 0] = __float2half(acc[6 + l * 3 + 0]);
        rb.h[l * 4 + 1] = __float2half(acc[6 + l * 3 + 1]);
        rb.h[l * 4 + 2] = __float2half(acc[6 + l * 3 + 2]);
        rb.h[l * 4 + 3] = __float2half(0.0f);
    }
    int rec = ((face * 64 + (yrow >> 1)) * 128 + x) * 2 + (yrow & 1);
    blurp[(size_t)rec * 2 + 0] = ra.f4;
    blurp[(size_t)rec * 2 + 1] = rb.f4;
}

// ---------------------------------------------------------------------------
// Build neighborhood records for bg1 (LDS-tiled, 16x16 recs per block)
// ---------------------------------------------------------------------------
template <int W>
__global__ __launch_bounds__(256)
void pack_nbhd(const float* __restrict__ src, float4* __restrict__ dst) {
    __shared__ float t[17][17 * 3];
    const int TB = W / 16;
    int bx = blockIdx.x % TB;
    int by = (blockIdx.x / TB) % TB;
    int f  = blockIdx.x / (TB * TB);

    for (int i = threadIdx.x; i < 17 * 17; i += 256) {
        int lx = i % 17, ly = i / 17;
        int gx = min(bx * 16 + lx, W - 1);
        int gy = min(by * 16 + ly, W - 1);
        const float* p = src + ((size_t)(f * W + gy) * W + gx) * 3;
        t[ly][lx * 3 + 0] = p[0];
        t[ly][lx * 3 + 1] = p[1];
        t[ly][lx * 3 + 2] = p[2];
    }
    __syncthreads();

    int tx = threadIdx.x & 15, ty = threadIdx.x >> 4;
    H8U qa, qb;
#pragma unroll
    for (int k = 0; k < 3; ++k) {
        qa.h[k]     = __float2half(t[ty][tx * 3 + k]);
        qa.h[4 + k] = __float2half(t[ty][(tx + 1) * 3 + k]);
        qb.h[k]     = __float2half(t[ty + 1][tx * 3 + k]);
        qb.h[4 + k] = __float2half(t[ty + 1][(tx + 1) * 3 + k]);
    }
    qa.h[3] = __float2half(0.0f); qa.h[7] = __float2half(0.0f);
    qb.h[3] = __float2half(0.0f); qb.h[7] = __float2half(0.0f);

    size_t rec = (size_t)(f * W + by * 16 + ty) * W + bx * 16 + tx;
    dst[rec * 2 + 0] = qa.f4;
    dst[rec * 2 + 1] = qb.f4;
}

// ---------------------------------------------------------------------------
// Fallback pack: f32 RGB -> 8B half4 tiled (bg1 only, if ws too small)
// ---------------------------------------------------------------------------
__global__ __launch_bounds__(256)
void pack_tiled(const float* __restrict__ src, float2* __restrict__ dst,
                int H, int W, int total) {
    int i = blockIdx.x * blockDim.x + threadIdx.x;
    if (i >= total) return;
    int x = i % W;
    int y = (i / W) % H;
    int f = i / (W * H);
    H4U u;
    u.h[0] = __float2half(src[(size_t)i * 3 + 0]);
    u.h[1] = __float2half(src[(size_t)i * 3 + 1]);
    u.h[2] = __float2half(src[(size_t)i * 3 + 2]);
    u.h[3] = __float2half(0.0f);
    int idx = ((f * (H >> 1) + (y >> 1)) * W + x) * 2 + (y & 1);
    dst[idx] = u.f2;
}

// ---------------------------------------------------------------------------
// Per-ray shading body
// ---------------------------------------------------------------------------
template <bool NB1>
__device__ inline void shade_one(float x, float y, float z, float sa,
                                 const float4* __restrict__ bg0n,
                                 const float4* __restrict__ bg1n,
                                 const float2* __restrict__ bg1p,
                                 const float4* __restrict__ blurp,
                                 float* __restrict__ R) {
    int face; float u, v;
    cube_coords(x, y, z, face, u, v);

    const float saTexel = (float)(4.0 * M_PI / (6.0 * 512.0 * 512.0));
    float m = logf(sa / saTexel);
    m = m / 1.3862943611198906f;   // f32(log(4))
    m = m * 0.5f;
    m = fminf(fmaxf(m, 0.0f), 3.0f);

    if (m >= 2.0f) {
        BLR b = bl_rec(u, v, face);
        H8U q00a, q00b, q10a, q10b, q01a, q01b, q11a, q11b;
        q00a.f4 = blurp[b.r00 * 2 + 0]; q00b.f4 = blurp[b.r00 * 2 + 1];
        q10a.f4 = blurp[b.r10 * 2 + 0]; q10b.f4 = blurp[b.r10 * 2 + 1];
        q01a.f4 = blurp[b.r01 * 2 + 0]; q01b.f4 = blurp[b.r01 * 2 + 1];
        q11a.f4 = blurp[b.r11 * 2 + 0]; q11b.f4 = blurp[b.r11 * 2 + 1];

        float w0 = 1.0f - fminf(fabsf(3.0f - m), 1.0f);
        float w1 = 1.0f - fminf(fabsf(2.5f - m), 1.0f);
        float w2 = 1.0f - fminf(fabsf(2.0f - m), 1.0f);
        float w3 = 1.0f - fminf(fabsf(1.5f - m), 1.0f);

        float b0 = 0.f, b1 = 0.f, b2 = 0.f;
        accum_level(q00a, q10a, q01a, q11a, 0, w0, b.wx, b.wy, b0, b1, b2);
        accum_level(q00a, q10a, q01a, q11a, 4, w1, b.wx, b.wy, b0, b1, b2);
        accum_level(q00b, q10b, q01b, q11b, 0, w2, b.wx, b.wy, b0, b1, b2);
        accum_level(q00b, q10b, q01b, q11b, 4, w3, b.wx, b.wy, b0, b1, b2);

        float denom = fmaxf(w0 + w1 + w2 + w3, 1e-8f);
        R[0] = b0 / denom; R[1] = b1 / denom; R[2] = b2 / denom;
    } else {
        int r0i; float wx0, wy0;
        nb_setup(u, v, 128, face, r0i, wx0, wy0);
        float c0[3], c1[3];
        nb_fetch(bg0n, r0i, wx0, wy0, c0);
        if (NB1) {
            int r1i; float wx1, wy1;
            nb_setup(u, v, 512, face, r1i, wx1, wy1);
            nb_fetch(bg1n, r1i, wx1, wy1, c1);
        } else {
            BLT b512 = bl_tiled(u, v, 512, 512, face);
            fetch_bl(bg1p, b512, c1);
        }
        R[0] = c0[0] + 0.5f * c1[0];
        R[1] = c0[1] + 0.5f * c1[1];
        R[2] = c0[2] + 0.5f * c1[2];
    }
}

// ---------------------------------------------------------------------------
// Shade: 4 rays per thread, vectorized stream I/O.
// ---------------------------------------------------------------------------
template <bool NB1>
__global__ __launch_bounds__(256)
void shade4(const float4* __restrict__ vd4, const float4* __restrict__ sa4,
            const float4* __restrict__ bg0n, const float4* __restrict__ bg1n,
            const float2* __restrict__ bg1p, const float4* __restrict__ blurp,
            float4* __restrict__ out4, int nquads) {
    int q = blockIdx.x * blockDim.x + threadIdx.x;
    if (q >= nquads) return;

    float4 a = vd4[3 * q + 0];
    float4 b = vd4[3 * q + 1];
    float4 c = vd4[3 * q + 2];
    float4 s = sa4[q];

    float X[4] = {a.x, a.w, b.z, c.y};
    float Y[4] = {a.y, b.x, b.w, c.z};
    float Z[4] = {a.z, b.y, c.x, c.w};
    float S[4] = {s.x, s.y, s.z, s.w};

    float R[12];
#pragma unroll
    for (int r = 0; r < 4; ++r) {
        shade_one<NB1>(X[r], Y[r], Z[r], S[r], bg0n, bg1n, bg1p, blurp, &R[3 * r]);
    }

    out4[3 * q + 0] = make_float4(R[0], R[1], R[2],  R[3]);
    out4[3 * q + 1] = make_float4(R[4], R[5], R[6],  R[7]);
    out4[3 * q + 2] = make_float4(R[8], R[9], R[10], R[11]);
}

// ---------------------------------------------------------------------------
extern "C" void kernel_launch(void* const* d_in, const int* in_sizes, int n_in,
                              void* d_out, int out_size, void* d_ws, size_t ws_size,
                              hipStream_t stream) {
    const float* viewdirs = (const float*)d_in[0];   // (B,3)
    const float* saSample = (const float*)d_in[1];   // (B,1)
    const float* bg0      = (const float*)d_in[2];   // (6,128,128,3)
    const float* bg1      = (const float*)d_in[3];   // (6,512,512,3)
    float* out = (float*)d_out;

    int B = in_sizes[0] / 3;

    // ws layout (nbhd mode, 56.6 MB):
    //   blurp : 196608 float4 (3.0 MB)
    //   bg0n  : 196608 float4 (3.0 MB)
    //   bg1n  : 3145728 float4 (50.3 MB); tmp (9.4 MB) aliases its head
    //           (tmp dead before pack_nbhd<512> runs)
    // fallback (18.6 MB): bg1p (12.6 MB) instead of bg1n; tmp aliases bg1p.
    float4* blurp = (float4*)d_ws;
    float4* bg0n  = blurp + 196608;
    const size_t NEED_NB = (size_t)(196608 + 196608 + 3145728) * 16;
    bool nb1 = ws_size >= NEED_NB;

    float4* bg1n = bg0n + 196608;
    float2* bg1p = (float2*)(bg0n + 196608);
    float4* tmp  = bg0n + 196608;   // alias; dead before bg1 pack

    blur_h4<<<6 * 128, 128, 0, stream>>>(bg0, tmp, bg0n);
    blur_v4<<<6 * 128, 128, 0, stream>>>(tmp, blurp);

    if (nb1) {
        pack_nbhd<512><<<6 * 32 * 32, 256, 0, stream>>>(bg1, bg1n);
    } else {
        int t1 = 6 * 512 * 512;
        pack_tiled<<<(t1 + 255) / 256, 256, 0, stream>>>(bg1, bg1p, 512, 512, t1);
    }

    int nquads = B / 4;
    int blocks = (nquads + 255) / 256;
    if (nb1) {
        shade4<true><<<blocks, 256, 0, stream>>>((const float4*)viewdirs,
                                                 (const float4*)saSample,
                                                 bg0n, bg1n, bg1p, blurp,
                                                 (float4*)out, nquads);
    } else {
        shade4<false><<<blocks, 256, 0, stream>>>((const float4*)viewdirs,
                                                  (const float4*)saSample,
                                                  bg0n, bg1n, bg1p, blurp,
                                                  (float4*)out, nquads);
    }
}